// Round 4
// baseline (432.649 us; speedup 1.0000x reference)
//
#include <hip/hip_runtime.h>
#include <math.h>

#define NTOK 4096
#define CCH  64
#define LOG2E 1.4426950408889634f
#define NSPLIT 4   // KV-split ways

typedef __attribute__((ext_vector_type(8)))  short bf16x8;   // 8 bf16 = 4 VGPRs
typedef __attribute__((ext_vector_type(4)))  float f32x4;
typedef __attribute__((ext_vector_type(16))) float f32x16;
typedef __attribute__((ext_vector_type(2)))  unsigned int uint32x2;

__device__ __forceinline__ unsigned short f2bf_rne(float f) {
    unsigned int u = __float_as_uint(f);
    u += 0x7FFFu + ((u >> 16) & 1u);
    return (unsigned short)(u >> 16);
}
__device__ __forceinline__ float bf2f(unsigned short u) {
    return __uint_as_float(((unsigned int)u) << 16);
}

// ---------------------------------------------------------------------------
// Kernel 1: MFMA projections (round-5 proven, unchanged except: zeroes the
// combine gate counters, one per (b, 64-token output group), via agent-scope
// stores so the following attn kernel's device-scope atomics see them).
// One GEMM per (b, 64-token tile): D[80x64] = [wv ; wq*log2e ; wk] * x_tile.
// Outputs qt/kt[b][n][8] (q pre-scaled by log2e) and
// vbf[b][c][tile*64 + sigma(nu)], sigma(nu) = 4*(nu&15) + (nu>>4).
// ---------------------------------------------------------------------------
__global__ __launch_bounds__(256) void proj_kernel(
    const float* __restrict__ x,
    const float* __restrict__ wq, const float* __restrict__ bq,
    const float* __restrict__ wk, const float* __restrict__ bk,
    const float* __restrict__ wv, const float* __restrict__ bv,
    unsigned short* __restrict__ qt, unsigned short* __restrict__ kt,
    unsigned short* __restrict__ vbf, unsigned int* __restrict__ cnt)
{
    __shared__ unsigned short xsb[64 * 68];  // [n][c] bf16 (B^T storage)
    __shared__ unsigned short wa[80 * 68];   // [m][c] bf16 (A storage)
    __shared__ unsigned short vtmp[64 * 66]; // [c][sigma(n)]
    __shared__ float bb[80];

    const int t  = threadIdx.x;
    const int b  = blockIdx.x >> 6;
    const int n0 = (blockIdx.x & 63) << 6;

    const int lane = t & 63;
    const int w    = t >> 6;
    const int l15  = lane & 15;
    const int g    = lane >> 4;

    // zero this block's gate counter for the attn kernel (grid == #counters)
    if (t == 0)
        __hip_atomic_store(&cnt[blockIdx.x], 0u, __ATOMIC_RELAXED,
                           __HIP_MEMORY_SCOPE_AGENT);

    {
        const int n  = t & 63;
        const int c0 = t >> 6;
        #pragma unroll
        for (int r = 0; r < 16; ++r) {
            const int c = c0 + 4 * r;
            xsb[n * 68 + c] = f2bf_rne(x[((size_t)(b * CCH + c)) * NTOK + n0 + n]);
        }
    }
    #pragma unroll
    for (int r = 0; r < 16; ++r) {
        const int i = t + 256 * r;
        wa[(i >> 6) * 68 + (i & 63)] = f2bf_rne(wv[i]);
    }
    {
        const int i0 = t, i1 = t + 256;
        wa[(64 + (i0 >> 6)) * 68 + (i0 & 63)] = f2bf_rne(wq[i0] * LOG2E);
        wa[(64 + (i1 >> 6)) * 68 + (i1 & 63)] = f2bf_rne(wq[i1] * LOG2E);
        wa[(72 + (i0 >> 6)) * 68 + (i0 & 63)] = f2bf_rne(wk[i0]);
        wa[(72 + (i1 >> 6)) * 68 + (i1 & 63)] = f2bf_rne(wk[i1]);
    }
    if (t < 80) {
        float bias;
        if (t < 64)      bias = bv[t];
        else if (t < 72) bias = bq[t - 64] * LOG2E;
        else             bias = bk[t - 72];
        bb[t] = bias;
    }
    __syncthreads();

    f32x4 acc[5];
    #pragma unroll
    for (int mt = 0; mt < 5; ++mt) acc[mt] = (f32x4){0.f, 0.f, 0.f, 0.f};
    #pragma unroll
    for (int kc = 0; kc < 2; ++kc) {
        const bf16x8 bx = *(const bf16x8*)&xsb[(w * 16 + l15) * 68 + kc * 32 + g * 8];
        #pragma unroll
        for (int mt = 0; mt < 5; ++mt) {
            const bf16x8 aw = *(const bf16x8*)&wa[(mt * 16 + l15) * 68 + kc * 32 + g * 8];
            acc[mt] = __builtin_amdgcn_mfma_f32_16x16x32_bf16(aw, bx, acc[mt], 0, 0, 0);
        }
    }

    const int n = w * 16 + l15;
    #pragma unroll
    for (int mt = 0; mt < 4; ++mt) {
        #pragma unroll
        for (int r = 0; r < 4; ++r) {
            const int c = mt * 16 + g * 4 + r;
            vtmp[c * 66 + 4 * l15 + w] = f2bf_rne(acc[mt][r] + bb[c]);
        }
    }
    {
        unsigned short vals[4];
        #pragma unroll
        for (int r = 0; r < 4; ++r)
            vals[r] = f2bf_rne(acc[4][r] + bb[64 + g * 4 + r]);
        const unsigned int lo = (unsigned int)vals[0] | ((unsigned int)vals[1] << 16);
        const unsigned int hi = (unsigned int)vals[2] | ((unsigned int)vals[3] << 16);
        unsigned short* dst = ((g < 2) ? qt : kt) +
                              ((size_t)(b * NTOK + n0 + n)) * 8 + (g & 1) * 4;
        *(uint32x2*)dst = (uint32x2){lo, hi};
    }
    __syncthreads();

    {
        const int c = t >> 2;
        const int q = t & 3;
        unsigned short* dst = vbf + ((size_t)(b * CCH + c)) * NTOK + n0 + q * 16;
        *(bf16x8*)dst       = *(const bf16x8*)&vtmp[c * 66 + q * 16];
        *(bf16x8*)(dst + 8) = *(const bf16x8*)&vtmp[c * 66 + q * 16 + 8];
    }
}

// ---------------------------------------------------------------------------
// Kernel 2: MFMA flash attention, KV-split 4 ways. MAIN LOOP IS BYTE-IDENTICAL
// to the proven 52.6us round-0 version (2 barriers/iter, single-buffered
// vs/ps, register prefetch, no setprio, launch_bounds(256,6)) — rounds 1-3
// proved any perturbation of that equilibrium collapses cross-block L2 reuse
// (FETCH 7.2 -> 155-265 MB). Round-14 change is EPILOGUE-ONLY: the combine
// kernel is fused here via a non-blocking last-of-4 gate:
//   - opart/lpart partials stored with agent-scope (sc1) stores: same
//     instruction count, write-through to the coherent point -> correct
//     under ANY workgroup->XCD placement (G16), no L2 invalidates issued.
//   - after the stores, t0 does threadfence + agent-scope fetch_add on
//     cnt[b*64 + m0/64]; old==3 elects the winner block, which combines its
//     64-token group (sum partials, *gamma/l, +x residual) reading partials
//     via agent-scope relaxed atomic loads (coherent, cache-state-neutral).
//   - no spin-waits: replay-safe, deadlock-free regardless of residency.
// ---------------------------------------------------------------------------
__global__ __launch_bounds__(256, 6) void attn_kernel(
    const unsigned short* __restrict__ qt, const unsigned short* __restrict__ kt,
    const unsigned short* __restrict__ vbf,
    unsigned short* __restrict__ opart, float* __restrict__ lpart,
    const float* __restrict__ x, const float* __restrict__ gamma_p,
    float* __restrict__ out, unsigned int* __restrict__ cnt, int B)
{
    __shared__ unsigned short vs[64 * 88];  // [c][n'] pre-permuted
    __shared__ unsigned short ps[64 * 88];  // [m][n'] bf16 P
    __shared__ float lsc[64];               // combine: gamma / l per token
    __shared__ int   winflag;

    const int t    = threadIdx.x;
    const int lane = t & 63;
    const int w    = t >> 6;
    const int bid  = blockIdx.x;
    const int b    = bid % B;                 // == bid & 7 for B=8 -> XCD id
    const int p    = (bid / B) % NSPLIT;
    const int m0   = (bid / (B * NSPLIT)) << 6;

    const int l15 = lane & 15;
    const int g   = lane >> 4;
    const int l31 = lane & 31;
    const int h   = lane >> 5;

    const int NIT     = 64 / NSPLIT;        // 16 KV tiles per block
    const int itStart = p * NIT;

    // ---- Q A-fragment direct from global (k>=8 rows zero) ----
    bf16x8 a_q = {};
    if (g == 0)
        a_q = *(const bf16x8*)&qt[((size_t)(b * NTOK + m0 + w * 16 + l15)) * 8];

    // ---- per-thread V staging pointers (two 16B chunks per thread) ----
    const int c0  = t >> 3, seg = t & 7;
    const int c1  = c0 + 32;
    const unsigned short* vsrc0 = vbf + ((size_t)(b * CCH + c0)) * NTOK
                                      + itStart * 64 + seg * 8;
    const unsigned short* vsrc1 = vbf + ((size_t)(b * CCH + c1)) * NTOK
                                      + itStart * 64 + seg * 8;
    unsigned short* vdst0 = &vs[c0 * 88 + seg * 8];
    unsigned short* vdst1 = &vs[c1 * 88 + seg * 8];

    // ---- K fragment source (only g==0 lanes load; others stay zero) ----
    const unsigned short* ksrc = kt + ((size_t)(b * NTOK + itStart * 64 + l15)) * 8;

    // ---- prefetch iteration 0 ----
    bf16x8 vreg0 = *(const bf16x8*)vsrc0;
    bf16x8 vreg1 = *(const bf16x8*)vsrc1;
    bf16x8 kr0 = {}, kr1 = {}, kr2 = {}, kr3 = {};
    if (g == 0) {
        kr0 = *(const bf16x8*)(ksrc);
        kr1 = *(const bf16x8*)(ksrc + 128);   // +16 tokens * 8
        kr2 = *(const bf16x8*)(ksrc + 256);
        kr3 = *(const bf16x8*)(ksrc + 384);
    }

    f32x16 oacc;
    #pragma unroll
    for (int i = 0; i < 16; ++i) oacc[i] = 0.f;
    float rs0 = 0.f, rs1 = 0.f, rs2 = 0.f, rs3 = 0.f;

    const int crow = ((w >> 1) * 32 + l31) * 88;
    const int mrow = ((w & 1) * 32 + l31) * 88;

    for (int it = 0; it < NIT; ++it) {
        __syncthreads();   // prev PV done reading vs/ps

        // ---- commit prefetched V tile to LDS (loaded one iteration ago) ----
        *(bf16x8*)vdst0 = vreg0;
        *(bf16x8*)vdst1 = vreg1;

        // ---- S = Q·K^T with current K regs ----
        const f32x4 z = {0.f, 0.f, 0.f, 0.f};
        f32x4 s0 = __builtin_amdgcn_mfma_f32_16x16x32_bf16(a_q, kr0, z, 0, 0, 0);
        f32x4 s1 = __builtin_amdgcn_mfma_f32_16x16x32_bf16(a_q, kr1, z, 0, 0, 0);
        f32x4 s2 = __builtin_amdgcn_mfma_f32_16x16x32_bf16(a_q, kr2, z, 0, 0, 0);
        f32x4 s3 = __builtin_amdgcn_mfma_f32_16x16x32_bf16(a_q, kr3, z, 0, 0, 0);

        // ---- prefetch next iteration's V + K into registers ----
        if (it + 1 < NIT) {
            vsrc0 += 64;  vsrc1 += 64;  ksrc += 64 * 8;
            vreg0 = *(const bf16x8*)vsrc0;
            vreg1 = *(const bf16x8*)vsrc1;
            if (g == 0) {
                kr0 = *(const bf16x8*)(ksrc);
                kr1 = *(const bf16x8*)(ksrc + 128);
                kr2 = *(const bf16x8*)(ksrc + 256);
                kr3 = *(const bf16x8*)(ksrc + 384);
            }
        }

        // ---- P = exp2(S) (q carries log2e), raw v_exp_f32 ----
        #pragma unroll
        for (int r = 0; r < 4; ++r) {
            const float p0 = __builtin_amdgcn_exp2f(s0[r]);
            const float p1 = __builtin_amdgcn_exp2f(s1[r]);
            const float p2 = __builtin_amdgcn_exp2f(s2[r]);
            const float p3 = __builtin_amdgcn_exp2f(s3[r]);
            const unsigned int lo = __builtin_amdgcn_perm(
                __float_as_uint(p1), __float_as_uint(p0), 0x07060302u);
            const unsigned int hi = __builtin_amdgcn_perm(
                __float_as_uint(p3), __float_as_uint(p2), 0x07060302u);
            *(uint32x2*)&ps[(w * 16 + g * 4 + r) * 88 + 4 * l15] = (uint32x2){lo, hi};
            const float ssum = (p0 + p1) + (p2 + p3);
            if      (r == 0) rs0 += ssum;
            else if (r == 1) rs1 += ssum;
            else if (r == 2) rs2 += ssum;
            else             rs3 += ssum;
        }
        __syncthreads();   // vs + ps ready

        // ---- O^T += V·P^T (4 MFMAs 32x32x16) ----
        #pragma unroll
        for (int kc = 0; kc < 4; ++kc) {
            const bf16x8 a_v = *(const bf16x8*)&vs[crow + kc * 16 + h * 8];
            const bf16x8 b_p = *(const bf16x8*)&ps[mrow + kc * 16 + h * 8];
            oacc = __builtin_amdgcn_mfma_f32_32x32x16_bf16(a_v, b_p, oacc, 0, 0, 0);
        }
    }

    #pragma unroll
    for (int xm = 1; xm <= 8; xm <<= 1) {
        rs0 += __shfl_xor(rs0, xm);
        rs1 += __shfl_xor(rs1, xm);
        rs2 += __shfl_xor(rs2, xm);
        rs3 += __shfl_xor(rs3, xm);
    }
    if (l15 == 0) {
        float* lp = lpart + (size_t)(p * B + b) * NTOK + m0 + w * 16 + g * 4;
        __hip_atomic_store(&lp[0], rs0, __ATOMIC_RELAXED, __HIP_MEMORY_SCOPE_AGENT);
        __hip_atomic_store(&lp[1], rs1, __ATOMIC_RELAXED, __HIP_MEMORY_SCOPE_AGENT);
        __hip_atomic_store(&lp[2], rs2, __ATOMIC_RELAXED, __HIP_MEMORY_SCOPE_AGENT);
        __hip_atomic_store(&lp[3], rs3, __ATOMIC_RELAXED, __HIP_MEMORY_SCOPE_AGENT);
    }
    {
        const int mloc = (w & 1) * 32 + l31;
        #pragma unroll
        for (int reg = 0; reg < 16; ++reg) {
            const int c = (w >> 1) * 32 + (reg & 3) + 8 * (reg >> 2) + 4 * h;
            __hip_atomic_store(
                &opart[((size_t)((p * B + b) * CCH + c)) * NTOK + m0 + mloc],
                f2bf_rne(oacc[reg]), __ATOMIC_RELAXED, __HIP_MEMORY_SCOPE_AGENT);
        }
    }

    // ---- fused combine: last-of-4 gate for this (b, m0) token group ----
    __syncthreads();          // all waves' partial stores issued + drained
    if (t == 0) {
        __threadfence();      // order stores before the gate increment
        const unsigned int old = __hip_atomic_fetch_add(
            &cnt[b * 64 + (m0 >> 6)], 1u,
            __ATOMIC_RELAXED, __HIP_MEMORY_SCOPE_AGENT);
        winflag = (old == 3u);
    }
    __syncthreads();
    if (!winflag) return;

    // winner: combine the 4 partials for tokens [m0, m0+64)
    const float gm = gamma_p[0];
    if (t < 64) {
        float s = 0.f;
        #pragma unroll
        for (int pp = 0; pp < NSPLIT; ++pp)
            s += __hip_atomic_load(
                &lpart[(size_t)(pp * B + b) * NTOK + m0 + t],
                __ATOMIC_RELAXED, __HIP_MEMORY_SCOPE_AGENT);
        lsc[t] = gm / s;
    }
    __syncthreads();

    const int cc = t >> 2, tq = t & 3;
    float acc2[16];
    #pragma unroll
    for (int j = 0; j < 16; ++j) acc2[j] = 0.f;
    #pragma unroll
    for (int pp = 0; pp < NSPLIT; ++pp) {
        const unsigned long long* src = (const unsigned long long*)
            &opart[((size_t)((pp * B + b) * CCH + cc)) * NTOK + m0 + tq * 16];
        #pragma unroll
        for (int q = 0; q < 4; ++q) {
            const unsigned long long v = __hip_atomic_load(
                src + q, __ATOMIC_RELAXED, __HIP_MEMORY_SCOPE_AGENT);
            acc2[q * 4 + 0] += bf2f((unsigned short)(v));
            acc2[q * 4 + 1] += bf2f((unsigned short)(v >> 16));
            acc2[q * 4 + 2] += bf2f((unsigned short)(v >> 32));
            acc2[q * 4 + 3] += bf2f((unsigned short)(v >> 48));
        }
    }
    const size_t rowo = ((size_t)(b * CCH + cc)) * NTOK + m0 + tq * 16;
    #pragma unroll
    for (int q = 0; q < 4; ++q) {
        const float4 xv = *(const float4*)&x[rowo + q * 4];
        float4 r;
        r.x = acc2[q * 4 + 0] * lsc[tq * 16 + q * 4 + 0] + xv.x;
        r.y = acc2[q * 4 + 1] * lsc[tq * 16 + q * 4 + 1] + xv.y;
        r.z = acc2[q * 4 + 2] * lsc[tq * 16 + q * 4 + 2] + xv.z;
        r.w = acc2[q * 4 + 3] * lsc[tq * 16 + q * 4 + 3] + xv.w;
        *(float4*)&out[rowo + q * 4] = r;
    }
}

extern "C" void kernel_launch(void* const* d_in, const int* in_sizes, int n_in,
                              void* d_out, int out_size, void* d_ws, size_t ws_size,
                              hipStream_t stream) {
    const float* x     = (const float*)d_in[0];
    const float* wq    = (const float*)d_in[1];
    const float* bq    = (const float*)d_in[2];
    const float* wk    = (const float*)d_in[3];
    const float* bk    = (const float*)d_in[4];
    const float* wv    = (const float*)d_in[5];
    const float* bv    = (const float*)d_in[6];
    const float* gamma = (const float*)d_in[7];
    float* out = (float*)d_out;

    int B = in_sizes[0] / (CCH * NTOK);   // 8

    // Workspace: qt | kt (512KB each) | vbf 4MB | opart bf16 16MB | lpart 512KB
    //            | cnt (B*64 u32 gate counters)
    unsigned short* wsp   = (unsigned short*)d_ws;
    unsigned short* qt    = wsp;
    unsigned short* kt    = qt + (size_t)B * NTOK * 8;
    unsigned short* vbf   = kt + (size_t)B * NTOK * 8;
    unsigned short* opart = vbf + (size_t)B * CCH * NTOK;
    float*          lpart = (float*)(opart + (size_t)NSPLIT * B * CCH * NTOK);
    unsigned int*   cnt   = (unsigned int*)(lpart + (size_t)NSPLIT * B * NTOK);

    proj_kernel<<<B * 64, 256, 0, stream>>>(x, wq, bq, wk, bk, wv, bv,
                                            qt, kt, vbf, cnt);
    attn_kernel<<<NSPLIT * B * 64, 256, 0, stream>>>(qt, kt, vbf, opart, lpart,
                                                     x, gamma, out, cnt, B);
}

// Round 5
// 125.272 us; speedup vs baseline: 3.4537x; 3.4537x over previous
//
#include <hip/hip_runtime.h>
#include <math.h>

#define NTOK 4096
#define CCH  64
#define LOG2E 1.4426950408889634f
#define NSPLIT 4   // KV-split ways

typedef __attribute__((ext_vector_type(8)))  short bf16x8;   // 8 bf16 = 4 VGPRs
typedef __attribute__((ext_vector_type(4)))  float f32x4;
typedef __attribute__((ext_vector_type(16))) float f32x16;
typedef __attribute__((ext_vector_type(2)))  unsigned int uint32x2;

__device__ __forceinline__ unsigned short f2bf_rne(float f) {
    unsigned int u = __float_as_uint(f);
    u += 0x7FFFu + ((u >> 16) & 1u);
    return (unsigned short)(u >> 16);
}
__device__ __forceinline__ float bf2f(unsigned short u) {
    return __uint_as_float(((unsigned int)u) << 16);
}

// ---------------------------------------------------------------------------
// RESTORATION of the verified 125.5us round-0 state. Session ledger:
//   r1: V direct-from-global (uncoalesced)      -> FETCH 259MB, 272us  FAILED
//   r2: V direct-from-global (coalesced layout) -> FETCH 265MB, 266us  FAILED
//       => traffic insensitive to coalescing: cross-block L2 reuse collapse
//   r3: dbuf vs/ps, 1 barrier, 3 blk/CU         -> FETCH 155MB, 109us  FAILED
//       => occupancy/phase change alone collapses the same reuse
//   r4: fused combine w/ agent-scope stores     -> WRITE 507MB, 376us  FAILED
//       => agent-scope bypasses XCD L2: 2B opart stores lose write-combining
// Law: attn's 52.6us IS its L2 equilibrium (FETCH 7.2MB = ~98% K/V L2 hit,
// WRITE 29MB = write-combined opart). It requires: LDS-staged V, plain
// stores, 2-barrier lockstep, 6 blk/CU nominal occupancy, bid%8 XCD decode.
// Do not perturb any of these.
// ---------------------------------------------------------------------------

// ---------------------------------------------------------------------------
// Kernel 1: MFMA projections. One GEMM per (b, 64-token tile):
// D[80x64] = [wv ; wq*log2e ; wk] * x_tile.
// Outputs qt/kt[b][n][8] (q pre-scaled by log2e) and
// vbf[b][c][tile*64 + sigma(nu)], sigma(nu) = 4*(nu&15) + (nu>>4).
// ---------------------------------------------------------------------------
__global__ __launch_bounds__(256) void proj_kernel(
    const float* __restrict__ x,
    const float* __restrict__ wq, const float* __restrict__ bq,
    const float* __restrict__ wk, const float* __restrict__ bk,
    const float* __restrict__ wv, const float* __restrict__ bv,
    unsigned short* __restrict__ qt, unsigned short* __restrict__ kt,
    unsigned short* __restrict__ vbf)
{
    __shared__ unsigned short xsb[64 * 68];  // [n][c] bf16 (B^T storage)
    __shared__ unsigned short wa[80 * 68];   // [m][c] bf16 (A storage)
    __shared__ unsigned short vtmp[64 * 66]; // [c][sigma(n)]
    __shared__ float bb[80];

    const int t  = threadIdx.x;
    const int b  = blockIdx.x >> 6;
    const int n0 = (blockIdx.x & 63) << 6;

    const int lane = t & 63;
    const int w    = t >> 6;
    const int l15  = lane & 15;
    const int g    = lane >> 4;

    {
        const int n  = t & 63;
        const int c0 = t >> 6;
        #pragma unroll
        for (int r = 0; r < 16; ++r) {
            const int c = c0 + 4 * r;
            xsb[n * 68 + c] = f2bf_rne(x[((size_t)(b * CCH + c)) * NTOK + n0 + n]);
        }
    }
    #pragma unroll
    for (int r = 0; r < 16; ++r) {
        const int i = t + 256 * r;
        wa[(i >> 6) * 68 + (i & 63)] = f2bf_rne(wv[i]);
    }
    {
        const int i0 = t, i1 = t + 256;
        wa[(64 + (i0 >> 6)) * 68 + (i0 & 63)] = f2bf_rne(wq[i0] * LOG2E);
        wa[(64 + (i1 >> 6)) * 68 + (i1 & 63)] = f2bf_rne(wq[i1] * LOG2E);
        wa[(72 + (i0 >> 6)) * 68 + (i0 & 63)] = f2bf_rne(wk[i0]);
        wa[(72 + (i1 >> 6)) * 68 + (i1 & 63)] = f2bf_rne(wk[i1]);
    }
    if (t < 80) {
        float bias;
        if (t < 64)      bias = bv[t];
        else if (t < 72) bias = bq[t - 64] * LOG2E;
        else             bias = bk[t - 72];
        bb[t] = bias;
    }
    __syncthreads();

    f32x4 acc[5];
    #pragma unroll
    for (int mt = 0; mt < 5; ++mt) acc[mt] = (f32x4){0.f, 0.f, 0.f, 0.f};
    #pragma unroll
    for (int kc = 0; kc < 2; ++kc) {
        const bf16x8 bx = *(const bf16x8*)&xsb[(w * 16 + l15) * 68 + kc * 32 + g * 8];
        #pragma unroll
        for (int mt = 0; mt < 5; ++mt) {
            const bf16x8 aw = *(const bf16x8*)&wa[(mt * 16 + l15) * 68 + kc * 32 + g * 8];
            acc[mt] = __builtin_amdgcn_mfma_f32_16x16x32_bf16(aw, bx, acc[mt], 0, 0, 0);
        }
    }

    const int n = w * 16 + l15;
    #pragma unroll
    for (int mt = 0; mt < 4; ++mt) {
        #pragma unroll
        for (int r = 0; r < 4; ++r) {
            const int c = mt * 16 + g * 4 + r;
            vtmp[c * 66 + 4 * l15 + w] = f2bf_rne(acc[mt][r] + bb[c]);
        }
    }
    {
        unsigned short vals[4];
        #pragma unroll
        for (int r = 0; r < 4; ++r)
            vals[r] = f2bf_rne(acc[4][r] + bb[64 + g * 4 + r]);
        const unsigned int lo = (unsigned int)vals[0] | ((unsigned int)vals[1] << 16);
        const unsigned int hi = (unsigned int)vals[2] | ((unsigned int)vals[3] << 16);
        unsigned short* dst = ((g < 2) ? qt : kt) +
                              ((size_t)(b * NTOK + n0 + n)) * 8 + (g & 1) * 4;
        *(uint32x2*)dst = (uint32x2){lo, hi};
    }
    __syncthreads();

    {
        const int c = t >> 2;
        const int q = t & 3;
        unsigned short* dst = vbf + ((size_t)(b * CCH + c)) * NTOK + n0 + q * 16;
        *(bf16x8*)dst       = *(const bf16x8*)&vtmp[c * 66 + q * 16];
        *(bf16x8*)(dst + 8) = *(const bf16x8*)&vtmp[c * 66 + q * 16 + 8];
    }
}

// ---------------------------------------------------------------------------
// Kernel 2: MFMA flash attention, KV-split 4 ways — the proven round-0 loop,
// byte-identical (2 barriers/iter, single-buffered vs/ps, register prefetch,
// plain stores, XCD-locality block decode bid%8 == b == XCD id).
// ---------------------------------------------------------------------------
__global__ __launch_bounds__(256, 6) void attn_kernel(
    const unsigned short* __restrict__ qt, const unsigned short* __restrict__ kt,
    const unsigned short* __restrict__ vbf,
    unsigned short* __restrict__ opart, float* __restrict__ lpart, int B)
{
    __shared__ unsigned short vs[64 * 88];  // [c][n'] pre-permuted
    __shared__ unsigned short ps[64 * 88];  // [m][n'] bf16 P

    const int t    = threadIdx.x;
    const int lane = t & 63;
    const int w    = t >> 6;
    const int bid  = blockIdx.x;
    const int b    = bid % B;                 // == bid & 7 for B=8 -> XCD id
    const int p    = (bid / B) % NSPLIT;
    const int m0   = (bid / (B * NSPLIT)) << 6;

    const int l15 = lane & 15;
    const int g   = lane >> 4;
    const int l31 = lane & 31;
    const int h   = lane >> 5;

    const int NIT     = 64 / NSPLIT;        // 16 KV tiles per block
    const int itStart = p * NIT;

    // ---- Q A-fragment direct from global (k>=8 rows zero) ----
    bf16x8 a_q = {};
    if (g == 0)
        a_q = *(const bf16x8*)&qt[((size_t)(b * NTOK + m0 + w * 16 + l15)) * 8];

    // ---- per-thread V staging pointers (two 16B chunks per thread) ----
    const int c0  = t >> 3, seg = t & 7;
    const int c1  = c0 + 32;
    const unsigned short* vsrc0 = vbf + ((size_t)(b * CCH + c0)) * NTOK
                                      + itStart * 64 + seg * 8;
    const unsigned short* vsrc1 = vbf + ((size_t)(b * CCH + c1)) * NTOK
                                      + itStart * 64 + seg * 8;
    unsigned short* vdst0 = &vs[c0 * 88 + seg * 8];
    unsigned short* vdst1 = &vs[c1 * 88 + seg * 8];

    // ---- K fragment source (only g==0 lanes load; others stay zero) ----
    const unsigned short* ksrc = kt + ((size_t)(b * NTOK + itStart * 64 + l15)) * 8;

    // ---- prefetch iteration 0 ----
    bf16x8 vreg0 = *(const bf16x8*)vsrc0;
    bf16x8 vreg1 = *(const bf16x8*)vsrc1;
    bf16x8 kr0 = {}, kr1 = {}, kr2 = {}, kr3 = {};
    if (g == 0) {
        kr0 = *(const bf16x8*)(ksrc);
        kr1 = *(const bf16x8*)(ksrc + 128);   // +16 tokens * 8
        kr2 = *(const bf16x8*)(ksrc + 256);
        kr3 = *(const bf16x8*)(ksrc + 384);
    }

    f32x16 oacc;
    #pragma unroll
    for (int i = 0; i < 16; ++i) oacc[i] = 0.f;
    float rs0 = 0.f, rs1 = 0.f, rs2 = 0.f, rs3 = 0.f;

    const int crow = ((w >> 1) * 32 + l31) * 88;
    const int mrow = ((w & 1) * 32 + l31) * 88;

    for (int it = 0; it < NIT; ++it) {
        __syncthreads();   // prev PV done reading vs/ps

        // ---- commit prefetched V tile to LDS (loaded one iteration ago) ----
        *(bf16x8*)vdst0 = vreg0;
        *(bf16x8*)vdst1 = vreg1;

        // ---- S = Q·K^T with current K regs ----
        const f32x4 z = {0.f, 0.f, 0.f, 0.f};
        f32x4 s0 = __builtin_amdgcn_mfma_f32_16x16x32_bf16(a_q, kr0, z, 0, 0, 0);
        f32x4 s1 = __builtin_amdgcn_mfma_f32_16x16x32_bf16(a_q, kr1, z, 0, 0, 0);
        f32x4 s2 = __builtin_amdgcn_mfma_f32_16x16x32_bf16(a_q, kr2, z, 0, 0, 0);
        f32x4 s3 = __builtin_amdgcn_mfma_f32_16x16x32_bf16(a_q, kr3, z, 0, 0, 0);

        // ---- prefetch next iteration's V + K into registers ----
        if (it + 1 < NIT) {
            vsrc0 += 64;  vsrc1 += 64;  ksrc += 64 * 8;
            vreg0 = *(const bf16x8*)vsrc0;
            vreg1 = *(const bf16x8*)vsrc1;
            if (g == 0) {
                kr0 = *(const bf16x8*)(ksrc);
                kr1 = *(const bf16x8*)(ksrc + 128);
                kr2 = *(const bf16x8*)(ksrc + 256);
                kr3 = *(const bf16x8*)(ksrc + 384);
            }
        }

        // ---- P = exp2(S) (q carries log2e), raw v_exp_f32 ----
        #pragma unroll
        for (int r = 0; r < 4; ++r) {
            const float p0 = __builtin_amdgcn_exp2f(s0[r]);
            const float p1 = __builtin_amdgcn_exp2f(s1[r]);
            const float p2 = __builtin_amdgcn_exp2f(s2[r]);
            const float p3 = __builtin_amdgcn_exp2f(s3[r]);
            const unsigned int lo = __builtin_amdgcn_perm(
                __float_as_uint(p1), __float_as_uint(p0), 0x07060302u);
            const unsigned int hi = __builtin_amdgcn_perm(
                __float_as_uint(p3), __float_as_uint(p2), 0x07060302u);
            *(uint32x2*)&ps[(w * 16 + g * 4 + r) * 88 + 4 * l15] = (uint32x2){lo, hi};
            const float ssum = (p0 + p1) + (p2 + p3);
            if      (r == 0) rs0 += ssum;
            else if (r == 1) rs1 += ssum;
            else if (r == 2) rs2 += ssum;
            else             rs3 += ssum;
        }
        __syncthreads();   // vs + ps ready

        // ---- O^T += V·P^T (4 MFMAs 32x32x16) ----
        #pragma unroll
        for (int kc = 0; kc < 4; ++kc) {
            const bf16x8 a_v = *(const bf16x8*)&vs[crow + kc * 16 + h * 8];
            const bf16x8 b_p = *(const bf16x8*)&ps[mrow + kc * 16 + h * 8];
            oacc = __builtin_amdgcn_mfma_f32_32x32x16_bf16(a_v, b_p, oacc, 0, 0, 0);
        }
    }

    #pragma unroll
    for (int xm = 1; xm <= 8; xm <<= 1) {
        rs0 += __shfl_xor(rs0, xm);
        rs1 += __shfl_xor(rs1, xm);
        rs2 += __shfl_xor(rs2, xm);
        rs3 += __shfl_xor(rs3, xm);
    }
    if (l15 == 0) {
        float* lp = lpart + (size_t)(p * B + b) * NTOK + m0 + w * 16 + g * 4;
        lp[0] = rs0; lp[1] = rs1; lp[2] = rs2; lp[3] = rs3;
    }
    {
        const int mloc = (w & 1) * 32 + l31;
        #pragma unroll
        for (int reg = 0; reg < 16; ++reg) {
            const int c = (w >> 1) * 32 + (reg & 3) + 8 * (reg >> 2) + 4 * h;
            opart[((size_t)((p * B + b) * CCH + c)) * NTOK + m0 + mloc] =
                f2bf_rne(oacc[reg]);
        }
    }
}

// ---------------------------------------------------------------------------
// Kernel 3: combine NSPLIT partials + normalize + residual (pure streaming).
// Grid 1024 (was 512): attn-neutral BW tweak on a grid-stride kernel.
// ---------------------------------------------------------------------------
__global__ __launch_bounds__(256) void combine_kernel(
    const unsigned short* __restrict__ opart, const float* __restrict__ lpart,
    const float* __restrict__ x, const float* __restrict__ gamma_p,
    float* __restrict__ out, int B)
{
    const float  gm      = gamma_p[0];
    const size_t nf4     = (size_t)B * CCH * NTOK / 4;
    const size_t ostride = (size_t)B * CCH * NTOK;
    for (size_t f = (size_t)blockIdx.x * 256 + threadIdx.x; f < nf4;
         f += (size_t)gridDim.x * 256) {
        const int m4 = ((int)(f & 1023)) * 4;
        const int bc = (int)(f >> 10);
        const int bi = bc >> 6;
        const size_t obase = (size_t)bc * NTOK + m4;

        float4 osum = {0.f, 0.f, 0.f, 0.f};
        float4 lsum = {0.f, 0.f, 0.f, 0.f};
        #pragma unroll
        for (int p = 0; p < NSPLIT; ++p) {
            const ushort4 o = *(const ushort4*)&opart[obase + (size_t)p * ostride];
            const float4  l = *(const float4*)&lpart[(size_t)(p * B + bi) * NTOK + m4];
            osum.x += bf2f(o.x); osum.y += bf2f(o.y);
            osum.z += bf2f(o.z); osum.w += bf2f(o.w);
            lsum.x += l.x; lsum.y += l.y; lsum.z += l.z; lsum.w += l.w;
        }
        const float4 xv = *(const float4*)&x[obase];
        float4 r;
        r.x = osum.x * gm / lsum.x + xv.x;
        r.y = osum.y * gm / lsum.y + xv.y;
        r.z = osum.z * gm / lsum.z + xv.z;
        r.w = osum.w * gm / lsum.w + xv.w;
        *(float4*)&out[obase] = r;
    }
}

extern "C" void kernel_launch(void* const* d_in, const int* in_sizes, int n_in,
                              void* d_out, int out_size, void* d_ws, size_t ws_size,
                              hipStream_t stream) {
    const float* x     = (const float*)d_in[0];
    const float* wq    = (const float*)d_in[1];
    const float* bq    = (const float*)d_in[2];
    const float* wk    = (const float*)d_in[3];
    const float* bk    = (const float*)d_in[4];
    const float* wv    = (const float*)d_in[5];
    const float* bv    = (const float*)d_in[6];
    const float* gamma = (const float*)d_in[7];
    float* out = (float*)d_out;

    int B = in_sizes[0] / (CCH * NTOK);   // 8

    // Workspace: qt | kt (512KB each) | vbf 4MB | opart bf16 16MB | lpart 512KB
    unsigned short* wsp   = (unsigned short*)d_ws;
    unsigned short* qt    = wsp;
    unsigned short* kt    = qt + (size_t)B * NTOK * 8;
    unsigned short* vbf   = kt + (size_t)B * NTOK * 8;
    unsigned short* opart = vbf + (size_t)B * CCH * NTOK;
    float*          lpart = (float*)(opart + (size_t)NSPLIT * B * CCH * NTOK);

    proj_kernel<<<B * 64, 256, 0, stream>>>(x, wq, bq, wk, bk, wv, bv, qt, kt, vbf);
    attn_kernel<<<NSPLIT * B * 64, 256, 0, stream>>>(qt, kt, vbf, opart, lpart, B);
    combine_kernel<<<1024, 256, 0, stream>>>(opart, lpart, x, gamma, out, B);
}

// Round 6
// 123.297 us; speedup vs baseline: 3.5090x; 1.0160x over previous
//
#include <hip/hip_runtime.h>
#include <math.h>

#define NTOK 4096
#define CCH  64
#define LOG2E 1.4426950408889634f
#define NSPLIT 2   // KV-split ways (r6: 4->2, see header note)

typedef __attribute__((ext_vector_type(8)))  short bf16x8;   // 8 bf16 = 4 VGPRs
typedef __attribute__((ext_vector_type(4)))  float f32x4;
typedef __attribute__((ext_vector_type(16))) float f32x16;
typedef __attribute__((ext_vector_type(2)))  unsigned int uint32x2;

__device__ __forceinline__ unsigned short f2bf_rne(float f) {
    unsigned int u = __float_as_uint(f);
    u += 0x7FFFu + ((u >> 16) & 1u);
    return (unsigned short)(u >> 16);
}
__device__ __forceinline__ float bf2f(unsigned short u) {
    return __uint_as_float(((unsigned int)u) << 16);
}

// ---------------------------------------------------------------------------
// Session ledger (keep):
//   r1: V direct-from-global (uncoalesced)      -> FETCH 259MB, 272us  FAILED
//   r2: V direct-from-global (coalesced layout) -> FETCH 265MB, 266us  FAILED
//   r3: dbuf vs/ps, 1 barrier, 3 blk/CU         -> FETCH 155MB, 109us  FAILED
//   r4: fused combine w/ agent-scope stores     -> WRITE 507MB, 376us  FAILED
//   r5: restoration of r0                        -> 125.3us, FETCH 7.2MB  OK
// Refined law: the 7MB-FETCH equilibrium = per-XCD working set (~640KB/batch)
// staying L2-resident, which requires the bid%8->XCD round-robin mapping to
// PERSIST. Mapping persists only while blocks are co-resident and progress
// uniformly; backfill dispatch into freed slots degrades it (r1-r4 all
// increased disorder). r6 attacks the one axis that IMPROVES mapping
// stability: NSPLIT 4->2 => grid 1024 = 4 blocks/CU, 100% co-resident from
// cycle 0, zero backfill phase, zero tail round. Inner loop byte-identical;
// per-CU total work invariant (4 blk x 32 it == 8 blk x 16 it).
// Go/no-go: FETCH must stay ~7-8MB; >30MB means collapse -> revert NSPLIT=4.
// ---------------------------------------------------------------------------

// ---------------------------------------------------------------------------
// Kernel 1: MFMA projections. One GEMM per (b, 64-token tile):
// D[80x64] = [wv ; wq*log2e ; wk] * x_tile.
// Outputs qt/kt[b][n][8] (q pre-scaled by log2e) and
// vbf[b][c][tile*64 + sigma(nu)], sigma(nu) = 4*(nu&15) + (nu>>4).
// ---------------------------------------------------------------------------
__global__ __launch_bounds__(256) void proj_kernel(
    const float* __restrict__ x,
    const float* __restrict__ wq, const float* __restrict__ bq,
    const float* __restrict__ wk, const float* __restrict__ bk,
    const float* __restrict__ wv, const float* __restrict__ bv,
    unsigned short* __restrict__ qt, unsigned short* __restrict__ kt,
    unsigned short* __restrict__ vbf)
{
    __shared__ unsigned short xsb[64 * 68];  // [n][c] bf16 (B^T storage)
    __shared__ unsigned short wa[80 * 68];   // [m][c] bf16 (A storage)
    __shared__ unsigned short vtmp[64 * 66]; // [c][sigma(n)]
    __shared__ float bb[80];

    const int t  = threadIdx.x;
    const int b  = blockIdx.x >> 6;
    const int n0 = (blockIdx.x & 63) << 6;

    const int lane = t & 63;
    const int w    = t >> 6;
    const int l15  = lane & 15;
    const int g    = lane >> 4;

    {
        const int n  = t & 63;
        const int c0 = t >> 6;
        #pragma unroll
        for (int r = 0; r < 16; ++r) {
            const int c = c0 + 4 * r;
            xsb[n * 68 + c] = f2bf_rne(x[((size_t)(b * CCH + c)) * NTOK + n0 + n]);
        }
    }
    #pragma unroll
    for (int r = 0; r < 16; ++r) {
        const int i = t + 256 * r;
        wa[(i >> 6) * 68 + (i & 63)] = f2bf_rne(wv[i]);
    }
    {
        const int i0 = t, i1 = t + 256;
        wa[(64 + (i0 >> 6)) * 68 + (i0 & 63)] = f2bf_rne(wq[i0] * LOG2E);
        wa[(64 + (i1 >> 6)) * 68 + (i1 & 63)] = f2bf_rne(wq[i1] * LOG2E);
        wa[(72 + (i0 >> 6)) * 68 + (i0 & 63)] = f2bf_rne(wk[i0]);
        wa[(72 + (i1 >> 6)) * 68 + (i1 & 63)] = f2bf_rne(wk[i1]);
    }
    if (t < 80) {
        float bias;
        if (t < 64)      bias = bv[t];
        else if (t < 72) bias = bq[t - 64] * LOG2E;
        else             bias = bk[t - 72];
        bb[t] = bias;
    }
    __syncthreads();

    f32x4 acc[5];
    #pragma unroll
    for (int mt = 0; mt < 5; ++mt) acc[mt] = (f32x4){0.f, 0.f, 0.f, 0.f};
    #pragma unroll
    for (int kc = 0; kc < 2; ++kc) {
        const bf16x8 bx = *(const bf16x8*)&xsb[(w * 16 + l15) * 68 + kc * 32 + g * 8];
        #pragma unroll
        for (int mt = 0; mt < 5; ++mt) {
            const bf16x8 aw = *(const bf16x8*)&wa[(mt * 16 + l15) * 68 + kc * 32 + g * 8];
            acc[mt] = __builtin_amdgcn_mfma_f32_16x16x32_bf16(aw, bx, acc[mt], 0, 0, 0);
        }
    }

    const int n = w * 16 + l15;
    #pragma unroll
    for (int mt = 0; mt < 4; ++mt) {
        #pragma unroll
        for (int r = 0; r < 4; ++r) {
            const int c = mt * 16 + g * 4 + r;
            vtmp[c * 66 + 4 * l15 + w] = f2bf_rne(acc[mt][r] + bb[c]);
        }
    }
    {
        unsigned short vals[4];
        #pragma unroll
        for (int r = 0; r < 4; ++r)
            vals[r] = f2bf_rne(acc[4][r] + bb[64 + g * 4 + r]);
        const unsigned int lo = (unsigned int)vals[0] | ((unsigned int)vals[1] << 16);
        const unsigned int hi = (unsigned int)vals[2] | ((unsigned int)vals[3] << 16);
        unsigned short* dst = ((g < 2) ? qt : kt) +
                              ((size_t)(b * NTOK + n0 + n)) * 8 + (g & 1) * 4;
        *(uint32x2*)dst = (uint32x2){lo, hi};
    }
    __syncthreads();

    {
        const int c = t >> 2;
        const int q = t & 3;
        unsigned short* dst = vbf + ((size_t)(b * CCH + c)) * NTOK + n0 + q * 16;
        *(bf16x8*)dst       = *(const bf16x8*)&vtmp[c * 66 + q * 16];
        *(bf16x8*)(dst + 8) = *(const bf16x8*)&vtmp[c * 66 + q * 16 + 8];
    }
}

// ---------------------------------------------------------------------------
// Kernel 2: MFMA flash attention, KV-split NSPLIT ways — the proven round-0
// inner loop, byte-identical (2 barriers/iter, single-buffered vs/ps,
// register prefetch, plain stores, bid%8 == b == XCD decode). Only the split
// count changed: NSPLIT=2 -> grid 1024 = 4 blocks/CU, all co-resident, NIT=32.
// ---------------------------------------------------------------------------
__global__ __launch_bounds__(256, 6) void attn_kernel(
    const unsigned short* __restrict__ qt, const unsigned short* __restrict__ kt,
    const unsigned short* __restrict__ vbf,
    unsigned short* __restrict__ opart, float* __restrict__ lpart, int B)
{
    __shared__ unsigned short vs[64 * 88];  // [c][n'] pre-permuted
    __shared__ unsigned short ps[64 * 88];  // [m][n'] bf16 P

    const int t    = threadIdx.x;
    const int lane = t & 63;
    const int w    = t >> 6;
    const int bid  = blockIdx.x;
    const int b    = bid % B;                 // == bid & 7 for B=8 -> XCD id
    const int p    = (bid / B) % NSPLIT;
    const int m0   = (bid / (B * NSPLIT)) << 6;

    const int l15 = lane & 15;
    const int g   = lane >> 4;
    const int l31 = lane & 31;
    const int h   = lane >> 5;

    const int NIT     = 64 / NSPLIT;        // 32 KV tiles per block
    const int itStart = p * NIT;

    // ---- Q A-fragment direct from global (k>=8 rows zero) ----
    bf16x8 a_q = {};
    if (g == 0)
        a_q = *(const bf16x8*)&qt[((size_t)(b * NTOK + m0 + w * 16 + l15)) * 8];

    // ---- per-thread V staging pointers (two 16B chunks per thread) ----
    const int c0  = t >> 3, seg = t & 7;
    const int c1  = c0 + 32;
    const unsigned short* vsrc0 = vbf + ((size_t)(b * CCH + c0)) * NTOK
                                      + itStart * 64 + seg * 8;
    const unsigned short* vsrc1 = vbf + ((size_t)(b * CCH + c1)) * NTOK
                                      + itStart * 64 + seg * 8;
    unsigned short* vdst0 = &vs[c0 * 88 + seg * 8];
    unsigned short* vdst1 = &vs[c1 * 88 + seg * 8];

    // ---- K fragment source (only g==0 lanes load; others stay zero) ----
    const unsigned short* ksrc = kt + ((size_t)(b * NTOK + itStart * 64 + l15)) * 8;

    // ---- prefetch iteration 0 ----
    bf16x8 vreg0 = *(const bf16x8*)vsrc0;
    bf16x8 vreg1 = *(const bf16x8*)vsrc1;
    bf16x8 kr0 = {}, kr1 = {}, kr2 = {}, kr3 = {};
    if (g == 0) {
        kr0 = *(const bf16x8*)(ksrc);
        kr1 = *(const bf16x8*)(ksrc + 128);   // +16 tokens * 8
        kr2 = *(const bf16x8*)(ksrc + 256);
        kr3 = *(const bf16x8*)(ksrc + 384);
    }

    f32x16 oacc;
    #pragma unroll
    for (int i = 0; i < 16; ++i) oacc[i] = 0.f;
    float rs0 = 0.f, rs1 = 0.f, rs2 = 0.f, rs3 = 0.f;

    const int crow = ((w >> 1) * 32 + l31) * 88;
    const int mrow = ((w & 1) * 32 + l31) * 88;

    for (int it = 0; it < NIT; ++it) {
        __syncthreads();   // prev PV done reading vs/ps

        // ---- commit prefetched V tile to LDS (loaded one iteration ago) ----
        *(bf16x8*)vdst0 = vreg0;
        *(bf16x8*)vdst1 = vreg1;

        // ---- S = Q·K^T with current K regs ----
        const f32x4 z = {0.f, 0.f, 0.f, 0.f};
        f32x4 s0 = __builtin_amdgcn_mfma_f32_16x16x32_bf16(a_q, kr0, z, 0, 0, 0);
        f32x4 s1 = __builtin_amdgcn_mfma_f32_16x16x32_bf16(a_q, kr1, z, 0, 0, 0);
        f32x4 s2 = __builtin_amdgcn_mfma_f32_16x16x32_bf16(a_q, kr2, z, 0, 0, 0);
        f32x4 s3 = __builtin_amdgcn_mfma_f32_16x16x32_bf16(a_q, kr3, z, 0, 0, 0);

        // ---- prefetch next iteration's V + K into registers ----
        if (it + 1 < NIT) {
            vsrc0 += 64;  vsrc1 += 64;  ksrc += 64 * 8;
            vreg0 = *(const bf16x8*)vsrc0;
            vreg1 = *(const bf16x8*)vsrc1;
            if (g == 0) {
                kr0 = *(const bf16x8*)(ksrc);
                kr1 = *(const bf16x8*)(ksrc + 128);
                kr2 = *(const bf16x8*)(ksrc + 256);
                kr3 = *(const bf16x8*)(ksrc + 384);
            }
        }

        // ---- P = exp2(S) (q carries log2e), raw v_exp_f32 ----
        #pragma unroll
        for (int r = 0; r < 4; ++r) {
            const float p0 = __builtin_amdgcn_exp2f(s0[r]);
            const float p1 = __builtin_amdgcn_exp2f(s1[r]);
            const float p2 = __builtin_amdgcn_exp2f(s2[r]);
            const float p3 = __builtin_amdgcn_exp2f(s3[r]);
            const unsigned int lo = __builtin_amdgcn_perm(
                __float_as_uint(p1), __float_as_uint(p0), 0x07060302u);
            const unsigned int hi = __builtin_amdgcn_perm(
                __float_as_uint(p3), __float_as_uint(p2), 0x07060302u);
            *(uint32x2*)&ps[(w * 16 + g * 4 + r) * 88 + 4 * l15] = (uint32x2){lo, hi};
            const float ssum = (p0 + p1) + (p2 + p3);
            if      (r == 0) rs0 += ssum;
            else if (r == 1) rs1 += ssum;
            else if (r == 2) rs2 += ssum;
            else             rs3 += ssum;
        }
        __syncthreads();   // vs + ps ready

        // ---- O^T += V·P^T (4 MFMAs 32x32x16) ----
        #pragma unroll
        for (int kc = 0; kc < 4; ++kc) {
            const bf16x8 a_v = *(const bf16x8*)&vs[crow + kc * 16 + h * 8];
            const bf16x8 b_p = *(const bf16x8*)&ps[mrow + kc * 16 + h * 8];
            oacc = __builtin_amdgcn_mfma_f32_32x32x16_bf16(a_v, b_p, oacc, 0, 0, 0);
        }
    }

    #pragma unroll
    for (int xm = 1; xm <= 8; xm <<= 1) {
        rs0 += __shfl_xor(rs0, xm);
        rs1 += __shfl_xor(rs1, xm);
        rs2 += __shfl_xor(rs2, xm);
        rs3 += __shfl_xor(rs3, xm);
    }
    if (l15 == 0) {
        float* lp = lpart + (size_t)(p * B + b) * NTOK + m0 + w * 16 + g * 4;
        lp[0] = rs0; lp[1] = rs1; lp[2] = rs2; lp[3] = rs3;
    }
    {
        const int mloc = (w & 1) * 32 + l31;
        #pragma unroll
        for (int reg = 0; reg < 16; ++reg) {
            const int c = (w >> 1) * 32 + (reg & 3) + 8 * (reg >> 2) + 4 * h;
            opart[((size_t)((p * B + b) * CCH + c)) * NTOK + m0 + mloc] =
                f2bf_rne(oacc[reg]);
        }
    }
}

// ---------------------------------------------------------------------------
// Kernel 3: combine NSPLIT partials + normalize + residual (pure streaming).
// ---------------------------------------------------------------------------
__global__ __launch_bounds__(256) void combine_kernel(
    const unsigned short* __restrict__ opart, const float* __restrict__ lpart,
    const float* __restrict__ x, const float* __restrict__ gamma_p,
    float* __restrict__ out, int B)
{
    const float  gm      = gamma_p[0];
    const size_t nf4     = (size_t)B * CCH * NTOK / 4;
    const size_t ostride = (size_t)B * CCH * NTOK;
    for (size_t f = (size_t)blockIdx.x * 256 + threadIdx.x; f < nf4;
         f += (size_t)gridDim.x * 256) {
        const int m4 = ((int)(f & 1023)) * 4;
        const int bc = (int)(f >> 10);
        const int bi = bc >> 6;
        const size_t obase = (size_t)bc * NTOK + m4;

        float4 osum = {0.f, 0.f, 0.f, 0.f};
        float4 lsum = {0.f, 0.f, 0.f, 0.f};
        #pragma unroll
        for (int p = 0; p < NSPLIT; ++p) {
            const ushort4 o = *(const ushort4*)&opart[obase + (size_t)p * ostride];
            const float4  l = *(const float4*)&lpart[(size_t)(p * B + bi) * NTOK + m4];
            osum.x += bf2f(o.x); osum.y += bf2f(o.y);
            osum.z += bf2f(o.z); osum.w += bf2f(o.w);
            lsum.x += l.x; lsum.y += l.y; lsum.z += l.z; lsum.w += l.w;
        }
        const float4 xv = *(const float4*)&x[obase];
        float4 r;
        r.x = osum.x * gm / lsum.x + xv.x;
        r.y = osum.y * gm / lsum.y + xv.y;
        r.z = osum.z * gm / lsum.z + xv.z;
        r.w = osum.w * gm / lsum.w + xv.w;
        *(float4*)&out[obase] = r;
    }
}

extern "C" void kernel_launch(void* const* d_in, const int* in_sizes, int n_in,
                              void* d_out, int out_size, void* d_ws, size_t ws_size,
                              hipStream_t stream) {
    const float* x     = (const float*)d_in[0];
    const float* wq    = (const float*)d_in[1];
    const float* bq    = (const float*)d_in[2];
    const float* wk    = (const float*)d_in[3];
    const float* bk    = (const float*)d_in[4];
    const float* wv    = (const float*)d_in[5];
    const float* bv    = (const float*)d_in[6];
    const float* gamma = (const float*)d_in[7];
    float* out = (float*)d_out;

    int B = in_sizes[0] / (CCH * NTOK);   // 8

    // Workspace: qt | kt (512KB each) | vbf 4MB | opart bf16 8MB | lpart 256KB
    unsigned short* wsp   = (unsigned short*)d_ws;
    unsigned short* qt    = wsp;
    unsigned short* kt    = qt + (size_t)B * NTOK * 8;
    unsigned short* vbf   = kt + (size_t)B * NTOK * 8;
    unsigned short* opart = vbf + (size_t)B * CCH * NTOK;
    float*          lpart = (float*)(opart + (size_t)NSPLIT * B * CCH * NTOK);

    proj_kernel<<<B * 64, 256, 0, stream>>>(x, wq, bq, wk, bk, wv, bv, qt, kt, vbf);
    attn_kernel<<<NSPLIT * B * 64, 256, 0, stream>>>(qt, kt, vbf, opart, lpart, B);
    combine_kernel<<<1024, 256, 0, stream>>>(opart, lpart, x, gamma, out, B);
}

// Round 7
// 121.843 us; speedup vs baseline: 3.5509x; 1.0119x over previous
//
#include <hip/hip_runtime.h>
#include <math.h>

#define NTOK 4096
#define CCH  64
#define LOG2E 1.4426950408889634f
#define NSPLIT 2   // KV-split ways

typedef __attribute__((ext_vector_type(8)))  short bf16x8;   // 8 bf16 = 4 VGPRs
typedef __attribute__((ext_vector_type(4)))  float f32x4;
typedef __attribute__((ext_vector_type(16))) float f32x16;
typedef __attribute__((ext_vector_type(2)))  unsigned int uint32x2;

__device__ __forceinline__ unsigned short f2bf_rne(float f) {
    unsigned int u = __float_as_uint(f);
    u += 0x7FFFu + ((u >> 16) & 1u);
    return (unsigned short)(u >> 16);
}
__device__ __forceinline__ float bf2f(unsigned short u) {
    return __uint_as_float(((unsigned int)u) << 16);
}

// ---------------------------------------------------------------------------
// Session ledger (keep):
//   r1: V direct-from-global (uncoalesced)      -> FETCH 259MB, 272us  FAILED
//   r2: V direct-from-global (coalesced layout) -> FETCH 265MB, 266us  FAILED
//   r3: dbuf vs/ps, 1 barrier, 3 blk/CU         -> FETCH 155MB, 109us  FAILED
//   r4: fused combine w/ agent-scope stores     -> WRITE 507MB, 376us  FAILED
//   r5: restoration of r0                        -> 125.3us, FETCH 7.2MB  OK
//   r6: NSPLIT 4->2 (grid 1024 = 4/CU, zero backfill) -> 123.3us,
//       FETCH 5.7MB, WRITE 15.6MB  WIN. attn dur unchanged ~49us at 5.5% HBM
//       -> attn is LATENCY-bound, not traffic-bound. Equilibrium held.
// Arithmetic across rounds: non-attn residual ~73-77us every round; r4
// (2-kernel) pins proj ~= 50us. proj is the new target: 2 waves/SIMD
// occupancy + 36 scalar f32 loads/thread + long serial chain.
// r7: proj rewrite ONLY (512 thr / 8 waves, float4 staging). attn + combine
// byte-identical to r6. Go/no-go: attn rows must stay ~49us / FETCH ~5.7MB.
// ---------------------------------------------------------------------------

// ---------------------------------------------------------------------------
// Kernel 1: MFMA projections, v2 (8 waves, vectorized staging).
// One GEMM per (b, 64-token tile): D[80x64] = [wv ; wq*log2e ; wk] * x_tile.
// Wave w: n-tile = w&3; m-tiles {0,1,2} for w<4, {3,4} for w>=4.
// Outputs qt/kt[b][n][8] (q pre-scaled by log2e) and
// vbf[b][c][tile*64 + sigma(nu)], sigma(nu) = 4*(nu&15) + (nu>>4)
// — all output bytes identical to v1.
// ---------------------------------------------------------------------------
__global__ __launch_bounds__(512) void proj_kernel(
    const float* __restrict__ x,
    const float* __restrict__ wq, const float* __restrict__ bq,
    const float* __restrict__ wk, const float* __restrict__ bk,
    const float* __restrict__ wv, const float* __restrict__ bv,
    unsigned short* __restrict__ qt, unsigned short* __restrict__ kt,
    unsigned short* __restrict__ vbf)
{
    __shared__ unsigned short xsb[64 * 68];  // [n][c] bf16 (B^T storage)
    __shared__ unsigned short wa[80 * 68];   // [m][c] bf16 (A storage)
    __shared__ unsigned short vtmp[64 * 66]; // [c][sigma(n)]
    __shared__ float bb[80];

    const int t  = threadIdx.x;
    const int b  = blockIdx.x >> 6;
    const int n0 = (blockIdx.x & 63) << 6;

    const int lane = t & 63;
    const int w    = t >> 6;          // 0..7
    const int l15  = lane & 15;
    const int g    = lane >> 4;
    const int nt   = w & 3;           // n-tile for MFMA phase

    // ---- stage x tile: 4096 f32 = 1024 float4; 2 per thread ----
    #pragma unroll
    for (int r = 0; r < 2; ++r) {
        const int i  = t + 512 * r;          // f4 index 0..1023
        const int c  = i >> 4;               // 0..63
        const int nq = (i & 15) * 4;         // n offset 0..60
        const float4 xv = *(const float4*)&x[((size_t)(b * CCH + c)) * NTOK + n0 + nq];
        xsb[(nq + 0) * 68 + c] = f2bf_rne(xv.x);
        xsb[(nq + 1) * 68 + c] = f2bf_rne(xv.y);
        xsb[(nq + 2) * 68 + c] = f2bf_rne(xv.z);
        xsb[(nq + 3) * 68 + c] = f2bf_rne(xv.w);
    }
    // ---- stage wv: 4096 f32 = 1024 float4; 2 per thread, packed 8B stores ----
    #pragma unroll
    for (int r = 0; r < 2; ++r) {
        const int i  = t + 512 * r;
        const int m  = i >> 4;
        const int cq = (i & 15) * 4;
        const float4 v = *(const float4*)&wv[i * 4];
        const unsigned int lo = (unsigned int)f2bf_rne(v.x) | ((unsigned int)f2bf_rne(v.y) << 16);
        const unsigned int hi = (unsigned int)f2bf_rne(v.z) | ((unsigned int)f2bf_rne(v.w) << 16);
        *(uint32x2*)&wa[m * 68 + cq] = (uint32x2){lo, hi};
    }
    // ---- stage wq (rows 64-71, x log2e) and wk (rows 72-79) ----
    if (t < 256) {
        const int half = t >> 7;             // 0: wq, 1: wk
        const int j    = t & 127;            // f4 index 0..127
        const int m    = 64 + half * 8 + (j >> 4);
        const int cq   = (j & 15) * 4;
        const float* src = half ? wk : wq;
        const float  sc  = half ? 1.f : LOG2E;
        const float4 v = *(const float4*)&src[j * 4];
        const unsigned int lo = (unsigned int)f2bf_rne(v.x * sc) | ((unsigned int)f2bf_rne(v.y * sc) << 16);
        const unsigned int hi = (unsigned int)f2bf_rne(v.z * sc) | ((unsigned int)f2bf_rne(v.w * sc) << 16);
        *(uint32x2*)&wa[m * 68 + cq] = (uint32x2){lo, hi};
    } else if (t < 336) {
        const int j = t - 256;               // 0..79
        float bias;
        if (j < 64)      bias = bv[j];
        else if (j < 72) bias = bq[j - 64] * LOG2E;
        else             bias = bk[j - 72];
        bb[j] = bias;
    }
    __syncthreads();

    // ---- MFMA: wave w covers n-tile nt, m-tiles [mtbase, mtbase+nmt) ----
    const int mtbase = (w < 4) ? 0 : 3;
    const int nmt    = (w < 4) ? 3 : 2;
    f32x4 acc[3];
    #pragma unroll
    for (int j = 0; j < 3; ++j) acc[j] = (f32x4){0.f, 0.f, 0.f, 0.f};
    #pragma unroll
    for (int kc = 0; kc < 2; ++kc) {
        const bf16x8 bx = *(const bf16x8*)&xsb[(nt * 16 + l15) * 68 + kc * 32 + g * 8];
        #pragma unroll
        for (int j = 0; j < 3; ++j) {
            if (j < nmt) {
                const bf16x8 aw = *(const bf16x8*)&wa[((mtbase + j) * 16 + l15) * 68 + kc * 32 + g * 8];
                acc[j] = __builtin_amdgcn_mfma_f32_16x16x32_bf16(aw, bx, acc[j], 0, 0, 0);
            }
        }
    }

    // ---- epilogue: V rows -> vtmp (sigma-permuted), q/k rows -> qt/kt ----
    #pragma unroll
    for (int j = 0; j < 3; ++j) {
        if (j < nmt) {
            const int mt = mtbase + j;
            if (mt < 4) {
                #pragma unroll
                for (int r = 0; r < 4; ++r) {
                    const int c = mt * 16 + g * 4 + r;
                    vtmp[c * 66 + 4 * l15 + nt] = f2bf_rne(acc[j][r] + bb[c]);
                }
            } else {   // mt == 4: q/k rows
                unsigned short vals[4];
                #pragma unroll
                for (int r = 0; r < 4; ++r)
                    vals[r] = f2bf_rne(acc[j][r] + bb[64 + g * 4 + r]);
                const unsigned int lo = (unsigned int)vals[0] | ((unsigned int)vals[1] << 16);
                const unsigned int hi = (unsigned int)vals[2] | ((unsigned int)vals[3] << 16);
                const int n = nt * 16 + l15;
                unsigned short* dst = ((g < 2) ? qt : kt) +
                                      ((size_t)(b * NTOK + n0 + n)) * 8 + (g & 1) * 4;
                *(uint32x2*)dst = (uint32x2){lo, hi};
            }
        }
    }
    __syncthreads();

    {
        const int c   = t >> 3;              // 0..63
        const int seg = t & 7;               // 8-token segment
        unsigned short* dst = vbf + ((size_t)(b * CCH + c)) * NTOK + n0 + seg * 8;
        *(bf16x8*)dst = *(const bf16x8*)&vtmp[c * 66 + seg * 8];
    }
}

// ---------------------------------------------------------------------------
// Kernel 2: MFMA flash attention, KV-split NSPLIT ways — byte-identical to
// the verified r6 kernel (2 barriers/iter, single-buffered vs/ps, register
// prefetch, plain stores, bid%8 == b == XCD decode, NSPLIT=2 -> grid 1024 =
// 4 blocks/CU all co-resident, NIT=32). DO NOT PERTURB.
// ---------------------------------------------------------------------------
__global__ __launch_bounds__(256, 6) void attn_kernel(
    const unsigned short* __restrict__ qt, const unsigned short* __restrict__ kt,
    const unsigned short* __restrict__ vbf,
    unsigned short* __restrict__ opart, float* __restrict__ lpart, int B)
{
    __shared__ unsigned short vs[64 * 88];  // [c][n'] pre-permuted
    __shared__ unsigned short ps[64 * 88];  // [m][n'] bf16 P

    const int t    = threadIdx.x;
    const int lane = t & 63;
    const int w    = t >> 6;
    const int bid  = blockIdx.x;
    const int b    = bid % B;                 // == bid & 7 for B=8 -> XCD id
    const int p    = (bid / B) % NSPLIT;
    const int m0   = (bid / (B * NSPLIT)) << 6;

    const int l15 = lane & 15;
    const int g   = lane >> 4;
    const int l31 = lane & 31;
    const int h   = lane >> 5;

    const int NIT     = 64 / NSPLIT;        // 32 KV tiles per block
    const int itStart = p * NIT;

    // ---- Q A-fragment direct from global (k>=8 rows zero) ----
    bf16x8 a_q = {};
    if (g == 0)
        a_q = *(const bf16x8*)&qt[((size_t)(b * NTOK + m0 + w * 16 + l15)) * 8];

    // ---- per-thread V staging pointers (two 16B chunks per thread) ----
    const int c0  = t >> 3, seg = t & 7;
    const int c1  = c0 + 32;
    const unsigned short* vsrc0 = vbf + ((size_t)(b * CCH + c0)) * NTOK
                                      + itStart * 64 + seg * 8;
    const unsigned short* vsrc1 = vbf + ((size_t)(b * CCH + c1)) * NTOK
                                      + itStart * 64 + seg * 8;
    unsigned short* vdst0 = &vs[c0 * 88 + seg * 8];
    unsigned short* vdst1 = &vs[c1 * 88 + seg * 8];

    // ---- K fragment source (only g==0 lanes load; others stay zero) ----
    const unsigned short* ksrc = kt + ((size_t)(b * NTOK + itStart * 64 + l15)) * 8;

    // ---- prefetch iteration 0 ----
    bf16x8 vreg0 = *(const bf16x8*)vsrc0;
    bf16x8 vreg1 = *(const bf16x8*)vsrc1;
    bf16x8 kr0 = {}, kr1 = {}, kr2 = {}, kr3 = {};
    if (g == 0) {
        kr0 = *(const bf16x8*)(ksrc);
        kr1 = *(const bf16x8*)(ksrc + 128);   // +16 tokens * 8
        kr2 = *(const bf16x8*)(ksrc + 256);
        kr3 = *(const bf16x8*)(ksrc + 384);
    }

    f32x16 oacc;
    #pragma unroll
    for (int i = 0; i < 16; ++i) oacc[i] = 0.f;
    float rs0 = 0.f, rs1 = 0.f, rs2 = 0.f, rs3 = 0.f;

    const int crow = ((w >> 1) * 32 + l31) * 88;
    const int mrow = ((w & 1) * 32 + l31) * 88;

    for (int it = 0; it < NIT; ++it) {
        __syncthreads();   // prev PV done reading vs/ps

        // ---- commit prefetched V tile to LDS (loaded one iteration ago) ----
        *(bf16x8*)vdst0 = vreg0;
        *(bf16x8*)vdst1 = vreg1;

        // ---- S = Q·K^T with current K regs ----
        const f32x4 z = {0.f, 0.f, 0.f, 0.f};
        f32x4 s0 = __builtin_amdgcn_mfma_f32_16x16x32_bf16(a_q, kr0, z, 0, 0, 0);
        f32x4 s1 = __builtin_amdgcn_mfma_f32_16x16x32_bf16(a_q, kr1, z, 0, 0, 0);
        f32x4 s2 = __builtin_amdgcn_mfma_f32_16x16x32_bf16(a_q, kr2, z, 0, 0, 0);
        f32x4 s3 = __builtin_amdgcn_mfma_f32_16x16x32_bf16(a_q, kr3, z, 0, 0, 0);

        // ---- prefetch next iteration's V + K into registers ----
        if (it + 1 < NIT) {
            vsrc0 += 64;  vsrc1 += 64;  ksrc += 64 * 8;
            vreg0 = *(const bf16x8*)vsrc0;
            vreg1 = *(const bf16x8*)vsrc1;
            if (g == 0) {
                kr0 = *(const bf16x8*)(ksrc);
                kr1 = *(const bf16x8*)(ksrc + 128);
                kr2 = *(const bf16x8*)(ksrc + 256);
                kr3 = *(const bf16x8*)(ksrc + 384);
            }
        }

        // ---- P = exp2(S) (q carries log2e), raw v_exp_f32 ----
        #pragma unroll
        for (int r = 0; r < 4; ++r) {
            const float p0 = __builtin_amdgcn_exp2f(s0[r]);
            const float p1 = __builtin_amdgcn_exp2f(s1[r]);
            const float p2 = __builtin_amdgcn_exp2f(s2[r]);
            const float p3 = __builtin_amdgcn_exp2f(s3[r]);
            const unsigned int lo = __builtin_amdgcn_perm(
                __float_as_uint(p1), __float_as_uint(p0), 0x07060302u);
            const unsigned int hi = __builtin_amdgcn_perm(
                __float_as_uint(p3), __float_as_uint(p2), 0x07060302u);
            *(uint32x2*)&ps[(w * 16 + g * 4 + r) * 88 + 4 * l15] = (uint32x2){lo, hi};
            const float ssum = (p0 + p1) + (p2 + p3);
            if      (r == 0) rs0 += ssum;
            else if (r == 1) rs1 += ssum;
            else if (r == 2) rs2 += ssum;
            else             rs3 += ssum;
        }
        __syncthreads();   // vs + ps ready

        // ---- O^T += V·P^T (4 MFMAs 32x32x16) ----
        #pragma unroll
        for (int kc = 0; kc < 4; ++kc) {
            const bf16x8 a_v = *(const bf16x8*)&vs[crow + kc * 16 + h * 8];
            const bf16x8 b_p = *(const bf16x8*)&ps[mrow + kc * 16 + h * 8];
            oacc = __builtin_amdgcn_mfma_f32_32x32x16_bf16(a_v, b_p, oacc, 0, 0, 0);
        }
    }

    #pragma unroll
    for (int xm = 1; xm <= 8; xm <<= 1) {
        rs0 += __shfl_xor(rs0, xm);
        rs1 += __shfl_xor(rs1, xm);
        rs2 += __shfl_xor(rs2, xm);
        rs3 += __shfl_xor(rs3, xm);
    }
    if (l15 == 0) {
        float* lp = lpart + (size_t)(p * B + b) * NTOK + m0 + w * 16 + g * 4;
        lp[0] = rs0; lp[1] = rs1; lp[2] = rs2; lp[3] = rs3;
    }
    {
        const int mloc = (w & 1) * 32 + l31;
        #pragma unroll
        for (int reg = 0; reg < 16; ++reg) {
            const int c = (w >> 1) * 32 + (reg & 3) + 8 * (reg >> 2) + 4 * h;
            opart[((size_t)((p * B + b) * CCH + c)) * NTOK + m0 + mloc] =
                f2bf_rne(oacc[reg]);
        }
    }
}

// ---------------------------------------------------------------------------
// Kernel 3: combine NSPLIT partials + normalize + residual (pure streaming).
// ---------------------------------------------------------------------------
__global__ __launch_bounds__(256) void combine_kernel(
    const unsigned short* __restrict__ opart, const float* __restrict__ lpart,
    const float* __restrict__ x, const float* __restrict__ gamma_p,
    float* __restrict__ out, int B)
{
    const float  gm      = gamma_p[0];
    const size_t nf4     = (size_t)B * CCH * NTOK / 4;
    const size_t ostride = (size_t)B * CCH * NTOK;
    for (size_t f = (size_t)blockIdx.x * 256 + threadIdx.x; f < nf4;
         f += (size_t)gridDim.x * 256) {
        const int m4 = ((int)(f & 1023)) * 4;
        const int bc = (int)(f >> 10);
        const int bi = bc >> 6;
        const size_t obase = (size_t)bc * NTOK + m4;

        float4 osum = {0.f, 0.f, 0.f, 0.f};
        float4 lsum = {0.f, 0.f, 0.f, 0.f};
        #pragma unroll
        for (int p = 0; p < NSPLIT; ++p) {
            const ushort4 o = *(const ushort4*)&opart[obase + (size_t)p * ostride];
            const float4  l = *(const float4*)&lpart[(size_t)(p * B + bi) * NTOK + m4];
            osum.x += bf2f(o.x); osum.y += bf2f(o.y);
            osum.z += bf2f(o.z); osum.w += bf2f(o.w);
            lsum.x += l.x; lsum.y += l.y; lsum.z += l.z; lsum.w += l.w;
        }
        const float4 xv = *(const float4*)&x[obase];
        float4 r;
        r.x = osum.x * gm / lsum.x + xv.x;
        r.y = osum.y * gm / lsum.y + xv.y;
        r.z = osum.z * gm / lsum.z + xv.z;
        r.w = osum.w * gm / lsum.w + xv.w;
        *(float4*)&out[obase] = r;
    }
}

extern "C" void kernel_launch(void* const* d_in, const int* in_sizes, int n_in,
                              void* d_out, int out_size, void* d_ws, size_t ws_size,
                              hipStream_t stream) {
    const float* x     = (const float*)d_in[0];
    const float* wq    = (const float*)d_in[1];
    const float* bq    = (const float*)d_in[2];
    const float* wk    = (const float*)d_in[3];
    const float* bk    = (const float*)d_in[4];
    const float* wv    = (const float*)d_in[5];
    const float* bv    = (const float*)d_in[6];
    const float* gamma = (const float*)d_in[7];
    float* out = (float*)d_out;

    int B = in_sizes[0] / (CCH * NTOK);   // 8

    // Workspace: qt | kt (512KB each) | vbf 4MB | opart bf16 8MB | lpart 256KB
    unsigned short* wsp   = (unsigned short*)d_ws;
    unsigned short* qt    = wsp;
    unsigned short* kt    = qt + (size_t)B * NTOK * 8;
    unsigned short* vbf   = kt + (size_t)B * NTOK * 8;
    unsigned short* opart = vbf + (size_t)B * CCH * NTOK;
    float*          lpart = (float*)(opart + (size_t)NSPLIT * B * CCH * NTOK);

    proj_kernel<<<B * 64, 512, 0, stream>>>(x, wq, bq, wk, bk, wv, bv, qt, kt, vbf);
    attn_kernel<<<NSPLIT * B * 64, 256, 0, stream>>>(qt, kt, vbf, opart, lpart, B);
    combine_kernel<<<1024, 256, 0, stream>>>(opart, lpart, x, gamma, out, B);
}